// Round 1
// baseline (156.210 us; speedup 1.0000x reference)
//
#include <hip/hip_runtime.h>
#include <hip/hip_bf16.h>

#define EMB 128
#define HID 11

// Each wave processes 2 tokens per iteration:
//   lanes  0..31 -> token 2w,   lanes 32..63 -> token 2w+1
//   lane covers 4 emb columns (float4): c0 = (lane&31)*4
// Hidden layer h[0..10] computed once per token on lanes (lane&31)<11,
// broadcast to the half-wave with __shfl (no LDS, no barriers).
__global__ __launch_bounds__(256, 4) void tabenc_kernel(
    const float* __restrict__ value,
    const int*   __restrict__ var_id,
    const int*   __restrict__ cmask,
    const float* __restrict__ W1,
    const float* __restrict__ b1,
    const float* __restrict__ W2,
    const float* __restrict__ emb,
    float*       __restrict__ out_sum,
    float*       __restrict__ out_pm,
    int n_tokens)
{
    const int tid  = threadIdx.x;
    const int lane = tid & 63;
    const int half = lane >> 5;      // which token of the pair
    const int sub  = lane & 31;      // lane within half-wave
    const int sb   = lane & 32;      // shfl source base (32*half)
    const int c0   = sub << 2;       // first of 4 emb columns

    // Hoist loop-invariant params into registers.
    float4 w2[HID];
#pragma unroll
    for (int h = 0; h < HID; ++h)
        w2[h] = *reinterpret_cast<const float4*>(W2 + h * EMB + c0);

    float w1v = 0.0f, b1v = 0.0f;
    if (sub < HID) { w1v = W1[sub]; b1v = b1[sub]; }

    const int gwave  = (blockIdx.x << 2) + (tid >> 6);
    const int nwaves = gridDim.x << 2;
    const int npair  = (n_tokens + 1) >> 1;

    for (int w = gwave; w < npair; w += nwaves) {
        int tok = 2 * w + half;
        // keep all lanes active for the shfl; clamp is benign (dup write of
        // identical data) and only triggers for odd n_tokens.
        if (tok >= n_tokens) tok = n_tokens - 1;

        const float v   = value[tok];
        const int   vid = var_id[tok];
        const float fm  = (float)cmask[tok];

        // one tanh pass; lanes sub>=11 compute tanh(0)=0 (w1v=b1v=0), unused
        const float hval = tanhf(fmaf(v, w1v, b1v));

        float ax = 0.f, ay = 0.f, az = 0.f, aw = 0.f;
#pragma unroll
        for (int hh = 0; hh < HID; ++hh) {
            const float hk = __shfl(hval, sb + hh, 64);
            ax = fmaf(hk, w2[hh].x, ax);
            ay = fmaf(hk, w2[hh].y, ay);
            az = fmaf(hk, w2[hh].z, az);
            aw = fmaf(hk, w2[hh].w, aw);
        }

        const float4 e = *reinterpret_cast<const float4*>(emb + vid * EMB + c0);
        float4 o;
        o.x = fmaf(ax, fm, e.x);
        o.y = fmaf(ay, fm, e.y);
        o.z = fmaf(az, fm, e.z);
        o.w = fmaf(aw, fm, e.w);

        *reinterpret_cast<float4*>(out_sum + tok * EMB + c0) = o;

        if (sub == 0) out_pm[tok] = (vid > 0) ? 1.0f : 0.0f;
    }
}

extern "C" void kernel_launch(void* const* d_in, const int* in_sizes, int n_in,
                              void* d_out, int out_size, void* d_ws, size_t ws_size,
                              hipStream_t stream) {
    const float* value  = (const float*)d_in[0];
    const int*   var_id = (const int*)  d_in[1];
    const int*   cmask  = (const int*)  d_in[2];
    const float* W1     = (const float*)d_in[3];
    const float* b1     = (const float*)d_in[4];
    const float* W2     = (const float*)d_in[5];
    const float* emb    = (const float*)d_in[6];

    const int n_tokens = in_sizes[0];              // 4096*200 = 819200
    float* out_sum = (float*)d_out;                // [n_tokens, 128]
    float* out_pm  = (float*)d_out + (long long)n_tokens * EMB;  // [n_tokens]

    const int waves_needed  = (n_tokens + 1) / 2;
    const int blocks_needed = (waves_needed + 3) / 4;
    const int grid = blocks_needed < 2048 ? blocks_needed : 2048;

    tabenc_kernel<<<grid, 256, 0, stream>>>(value, var_id, cmask, W1, b1, W2,
                                            emb, out_sum, out_pm, n_tokens);
}

// Round 2
// 98.274 us; speedup vs baseline: 1.5895x; 1.5895x over previous
//
#include <hip/hip_runtime.h>
#include <hip/hip_bf16.h>

#define EMB 128
#define HID 11

typedef float f32x4 __attribute__((ext_vector_type(4)));

// tanh(x) = sign(x) * (1 - 2/(exp(2|x|)+1)); v_exp_f32 + v_rcp_f32 fast path.
// |x| large -> exp = inf -> rcp = 0 -> result ±1 (correct saturation).
__device__ __forceinline__ float fast_tanh(float x) {
    float ax = fabsf(x);
    float e  = __expf(2.0f * ax);
    float r  = 1.0f - 2.0f * __builtin_amdgcn_rcpf(e + 1.0f);
    return copysignf(r, x);
}

// Wave layout: lanes 0..31 -> token 2w, lanes 32..63 -> token 2w+1.
// Each lane covers 4 emb columns (float4), c0 = (lane&31)*4.
// Unroll x2 over the grid stride: pairs w and w+nwaves per iteration, all
// loads (scalars + emb gathers) issued before compute for memory-level
// parallelism. Output stores are nontemporal (write-once stream) so the
// 512 KB emb table stays resident in L2.
__global__ __launch_bounds__(256, 4) void tabenc_kernel(
    const float* __restrict__ value,
    const int*   __restrict__ var_id,
    const int*   __restrict__ cmask,
    const float* __restrict__ W1,
    const float* __restrict__ b1,
    const float* __restrict__ W2,
    const float* __restrict__ emb,
    float*       __restrict__ out_sum,
    float*       __restrict__ out_pm,
    int n_tokens)
{
    const int tid  = threadIdx.x;
    const int lane = tid & 63;
    const int half = lane >> 5;
    const int sub  = lane & 31;
    const int sb   = lane & 32;      // shfl source base for this half-wave
    const int c0   = sub << 2;

    f32x4 w2[HID];
#pragma unroll
    for (int h = 0; h < HID; ++h)
        w2[h] = *reinterpret_cast<const f32x4*>(W2 + h * EMB + c0);

    float w1v = 0.0f, b1v = 0.0f;
    if (sub < HID) { w1v = W1[sub]; b1v = b1[sub]; }

    const int gwave  = (blockIdx.x << 2) + (tid >> 6);
    const int nwaves = gridDim.x << 2;
    const int nw2    = nwaves << 1;
    const int npair  = (n_tokens + 1) >> 1;
    const int tmax   = n_tokens - 1;

    for (int w = gwave; w < npair; w += nw2) {
        const int wB = w + nwaves;

        int tokA = 2 * w + half;          if (tokA > tmax) tokA = tmax;
        int tokB = 2 * wB + half;         if (tokB > tmax) tokB = tmax;
        const bool doB = (wB < npair);

        // ---- issue all loads first ----
        const float vA  = value[tokA];
        const int   idA = var_id[tokA];
        const int   cmA = cmask[tokA];
        const float vB  = value[tokB];
        const int   idB = var_id[tokB];
        const int   cmB = cmask[tokB];

        const f32x4 eA = *reinterpret_cast<const f32x4*>(emb + (long)idA * EMB + c0);
        const f32x4 eB = *reinterpret_cast<const f32x4*>(emb + (long)idB * EMB + c0);

        // ---- hidden layer (one fast tanh per token, lanes sub>=11 unused) ----
        const float hA = fast_tanh(fmaf(vA, w1v, b1v));
        const float hB = fast_tanh(fmaf(vB, w1v, b1v));

        f32x4 aA = {0.f, 0.f, 0.f, 0.f};
        f32x4 aB = {0.f, 0.f, 0.f, 0.f};
#pragma unroll
        for (int hh = 0; hh < HID; ++hh) {
            const float kA = __shfl(hA, sb + hh, 64);
            const float kB = __shfl(hB, sb + hh, 64);
            aA += kA * w2[hh];
            aB += kB * w2[hh];
        }

        const f32x4 oA = aA * (float)cmA + eA;
        const f32x4 oB = aB * (float)cmB + eB;

        __builtin_nontemporal_store(oA,
            reinterpret_cast<f32x4*>(out_sum + (long)tokA * EMB + c0));
        if (sub == 0)
            __builtin_nontemporal_store((idA > 0) ? 1.0f : 0.0f, out_pm + tokA);

        if (doB) {
            __builtin_nontemporal_store(oB,
                reinterpret_cast<f32x4*>(out_sum + (long)tokB * EMB + c0));
            if (sub == 0)
                __builtin_nontemporal_store((idB > 0) ? 1.0f : 0.0f, out_pm + tokB);
        }
    }
}

extern "C" void kernel_launch(void* const* d_in, const int* in_sizes, int n_in,
                              void* d_out, int out_size, void* d_ws, size_t ws_size,
                              hipStream_t stream) {
    const float* value  = (const float*)d_in[0];
    const int*   var_id = (const int*)  d_in[1];
    const int*   cmask  = (const int*)  d_in[2];
    const float* W1     = (const float*)d_in[3];
    const float* b1     = (const float*)d_in[4];
    const float* W2     = (const float*)d_in[5];
    const float* emb    = (const float*)d_in[6];

    const int n_tokens = in_sizes[0];              // 4096*200 = 819200
    float* out_sum = (float*)d_out;                // [n_tokens, 128]
    float* out_pm  = (float*)d_out + (long long)n_tokens * EMB;  // [n_tokens]

    const int waves_needed  = (n_tokens + 1) / 2;
    const int blocks_needed = (waves_needed + 3) / 4;
    const int grid = blocks_needed < 2048 ? blocks_needed : 2048;

    tabenc_kernel<<<grid, 256, 0, stream>>>(value, var_id, cmask, W1, b1, W2,
                                            emb, out_sum, out_pm, n_tokens);
}